// Round 5
// baseline (1775.137 us; speedup 1.0000x reference)
//
#include <hip/hip_runtime.h>

typedef unsigned short u16;
typedef unsigned int   u32;
typedef unsigned long long u64;
typedef short s8v __attribute__((ext_vector_type(8)));   // 8 x bf16 MFMA operand
typedef float f4v __attribute__((ext_vector_type(4)));   // MFMA accumulator
typedef unsigned short u16x4 __attribute__((ext_vector_type(4)));

#define DEV __device__ __forceinline__

DEV u16 f2b(float f){
  u32 x = __builtin_bit_cast(u32, f);
  u32 r = x + 0x7fffu + ((x >> 16) & 1u);
  return (u16)(r >> 16);
}
DEV float b2f(u16 u){ u32 x = ((u32)u) << 16; return __builtin_bit_cast(float, x); }
DEV f4v mfma16(s8v a, s8v b, f4v c){ return __builtin_amdgcn_mfma_f32_16x16x32_bf16(a, b, c, 0, 0, 0); }

DEV void segrange(const int* __restrict__ im, int P, int b, int& s0, int& s1){
  int lo = 0, hi = P;
  while (lo < hi){ int m = (lo + hi) >> 1; if (im[m] < b) lo = m + 1; else hi = m; }
  s0 = lo;
  int lo2 = lo; hi = P;
  while (lo2 < hi){ int m = (lo2 + hi) >> 1; if (im[m] < b + 1) lo2 = m + 1; else hi = m; }
  s1 = lo2;
}

DEV void transpose_body(const float* __restrict__ src, u16* __restrict__ dst,
                        int R, int C, int rb, int cb, int t, int nt, float* tile){
  int r0 = rb << 6, c0 = cb << 6;
  for (int i = t; i < 4096; i += nt){
    int rl = i >> 6, cl = i & 63;
    tile[rl*65 + cl] = src[(size_t)(r0 + rl)*C + c0 + cl];
  }
  __syncthreads();
  for (int i = t; i < 4096; i += nt){
    int cl = i >> 6, rl = i & 63;
    dst[(size_t)(c0 + cl)*R + r0 + rl] = f2b(tile[rl*65 + cl]);
  }
}

// ================= k_misc: small weight transforms + feature segment-mean ====================
// [0,64): w1t   [64,1216): w2t   [1216,2240): wuT   [2240,2440): featpool -> pfbf
__global__ __launch_bounds__(256) void k_misc(
    const float* __restrict__ feat, const int* __restrict__ pidx, const int* __restrict__ im_idx,
    const float* __restrict__ w_c1, const float* __restrict__ w_c2, const float* __restrict__ w_u,
    u16* __restrict__ w1t, u16* __restrict__ w2t, u16* __restrict__ wuT,
    u16* __restrict__ pfbf, int P){
  int bid = blockIdx.x, t = threadIdx.x;
  if (bid < 64){
    int i = bid*256 + t;                   // [128 oc][128 k]
    int k = i & 127;
    w1t[i] = f2b(k < 98 ? w_c1[(i>>7)*98 + k] : 0.f);
  } else if (bid < 1216){
    int i = (bid - 64)*256 + t;            // [9 tap][256 oc][128 ic]
    int tap = i >> 15, r = i & 32767;
    w2t[i] = f2b(w_c2[((r>>7)*128 + (r & 127))*9 + tap]);
  } else if (bid < 2240){
    int i = (bid - 1216)*256 + t;
    wuT[i] = f2b(w_u[i]);
  } else {
    int i = bid - 2240; int s = i/100, b = i - s*100;
    int s0, s1; segrange(im_idx, P, b, s0, s1);
    float inv = 1.f / fmaxf((float)(s1 - s0), 1.f);
    f4v a0 = {}, a1 = {};
    for (int p = s0; p < s1; ++p){
      int row = pidx[p*2 + s];
      const f4v* src = (const f4v*)(feat + (size_t)row*2048);
      a0 += src[t]; a1 += src[t+256];
    }
    u16* dst = pfbf + (size_t)(s*100 + b)*2048;
    #pragma unroll
    for (int j = 0; j < 4; ++j){
      dst[4*t + j]        = f2b(a0[j]*inv);
      dst[1024 + 4*t + j] = f2b(a1[j]*inv);
    }
  }
}

// ================= mega1: conv1 (LDS-bound) UNION union-pool (HBM-bound), interleaved =========
// union iff (bid&7)==7 (uidx=bid>>3 < 800); else conv1 cidx = bid - (bid>>3), valid < P
__global__ __launch_bounds__(256) void k_mega1(
    const float* __restrict__ masks, const u16* __restrict__ w1t, const float* __restrict__ b1,
    float* __restrict__ stats1, u16* __restrict__ spool,
    const float* __restrict__ uf, const int* __restrict__ im_idx, u16* __restrict__ muT, int P){
  __shared__ f4v raw4[3809];                 // 60944 B shared by both roles
  int bid = blockIdx.x, t = threadIdx.x;

  if ((bid & 7) == 7){
    // ---------- union segment-mean: block (b, icb8) pools 128 channels ----------
    float* usm = (float*)raw4;               // [128 ch][49 pix] f32
    int u = bid >> 3;
    int b = u >> 3, icb8 = u & 7;
    int s0, s1; segrange(im_idx, P, b, s0, s1);
    float inv = 1.f / fmaxf((float)(s1 - s0), 1.f);
    f4v a[6] = {}; f4v a6 = {};
    for (int p = s0; p < s1; ++p){
      const f4v* x = (const f4v*)(uf + (size_t)p*50176 + icb8*6272);
      #pragma unroll
      for (int j = 0; j < 6; ++j) a[j] += x[t + 256*j];
      if (t < 32) a6 += x[1536 + t];
    }
    f4v* us4 = (f4v*)usm;
    #pragma unroll
    for (int j = 0; j < 6; ++j) us4[t + 256*j] = a[j];
    if (t < 32) us4[1536 + t] = a6;
    __syncthreads();
    u16* dst = muT + (size_t)b*49*1024 + icb8*128;
    for (int o = t; o < 6272; o += 256){
      int icl = o & 127, pix = o >> 7;
      dst[(size_t)pix*1024 + icl] = f2b(usm[icl*49 + pix]*inv);
    }
    return;
  }

  // ---------- conv1 (7x7 s2 p3, 2->128): quad-k im2col, reg B, stats + u32 maxpool ----------
  int cidx = bid - (bid >> 3);
  if (cidx >= P) return;
  u16* in_bf = (u16*)raw4;                       // [2][33][33] padded input
  u16* a2col = (u16*)((char*)raw4 + 4368);       // [208 m][136 k]; reused as s1n[128][196]
  int p = cidx;
  int lane = t & 63, w = t >> 6;
  int l15 = lane & 15, lhi = lane >> 4;
  s8v Bf[4][2];
  #pragma unroll
  for (int kst = 0; kst < 4; ++kst){
    Bf[kst][0] = *(const s8v*)&w1t[(w*32 + l15)*128 + kst*32 + lhi*8];
    Bf[kst][1] = *(const s8v*)&w1t[(w*32 + 16 + l15)*128 + kst*32 + lhi*8];
  }
  for (int i = t; i < 1089; i += 256) ((u32*)in_bf)[i] = 0;
  for (int i = t; i < 768; i += 256){            // zero pad rows 196..207 (k<128)
    int r = i >> 6, c = i & 63;
    ((u32*)&a2col[(196 + r)*136])[c] = 0;
  }
  __syncthreads();
  for (int e = t; e < 1458; e += 256){
    int c = e >= 729; int r = e - c*729;
    int rr = r/27, cc = r - rr*27;
    in_bf[c*1089 + (rr + 3)*33 + cc + 3] = f2b(masks[(size_t)p*1458 + e]);
  }
  __syncthreads();
  {                                  // quad-k im2col: thread owns k = 4kq..4kq+3, pix = g, g+8, ...
    int kq = t & 31, g = t >> 5;
    int sb[4]; bool vd[4];
    #pragma unroll
    for (int j = 0; j < 4; ++j){
      int k = 4*kq + j;
      vd[j] = k < 98;
      int ic = k >= 49; int r = k - ic*49;
      int ky = r/7, kx = r - ky*7;
      sb[j] = ic*1089 + ky*33 + kx;
    }
    int oy = 0, ox = g;
    for (int pix = g; pix < 196; pix += 8){
      int base = oy*66 + ox*2;
      u16x4 v;
      #pragma unroll
      for (int j = 0; j < 4; ++j)
        v[j] = vd[j] ? in_bf[sb[j] + base] : (u16)0;
      *(u16x4*)&a2col[pix*136 + 4*kq] = v;
      ox += 8; if (ox >= 14){ ox -= 14; ++oy; }
    }
  }
  __syncthreads();
  f4v acc[13][2] = {};
  #pragma unroll
  for (int kst = 0; kst < 4; ++kst){
    int koff = kst*32 + lhi*8;
    #pragma unroll
    for (int mt = 0; mt < 13; ++mt){
      s8v A = *(const s8v*)&a2col[(mt*16 + l15)*136 + koff];
      acc[mt][0] = mfma16(A, Bf[kst][0], acc[mt][0]);
      acc[mt][1] = mfma16(A, Bf[kst][1], acc[mt][1]);
    }
  }
  __syncthreads();                       // all reads of a2col done before s1n overwrite
  u16* s1n = a2col;                      // [128 oc][196 pix], PRE-BN relu
  int ocb = w*32;
  float ss[2] = {0,0}, qq[2] = {0,0};
  #pragma unroll
  for (int n = 0; n < 2; ++n){
    int oc = ocb + n*16 + l15;
    float bias = b1[oc];
    #pragma unroll
    for (int mt = 0; mt < 13; ++mt)
      #pragma unroll
      for (int v = 0; v < 4; ++v){
        int pix = mt*16 + lhi*4 + v;
        if (pix < 196){
          float r = fmaxf(acc[mt][n][v] + bias, 0.f);
          ss[n] += r; qq[n] += r*r;
          s1n[oc*196 + pix] = f2b(r);
        }
      }
  }
  #pragma unroll
  for (int n = 0; n < 2; ++n){
    float s = ss[n], q = qq[n];
    s += __shfl_xor(s, 16); s += __shfl_xor(s, 32);
    q += __shfl_xor(q, 16); q += __shfl_xor(q, 32);
    if (lane < 16){
      atomicAdd(&stats1[ocb + n*16 + lane], s);
      atomicAdd(&stats1[128 + ocb + n*16 + lane], q);
    }
  }
  __syncthreads();
  {                                      // maxpool 3x3 s2 p1 via aligned u32 pair reads
    int oc = t & 127;                    // fixed per thread
    const u32* row32 = (const u32*)s1n;
    int pp0 = t >> 7;                    // 0 or 1, steps +2
    int poy = 0, pox = pp0;
    for (int pp = pp0; pp < 49; pp += 2){
      u32 m = 0;
      int iy0 = poy*2 - 1;
      #pragma unroll
      for (int dy = 0; dy < 3; ++dy){
        int iy = iy0 + dy;
        if (iy < 0 || iy > 13) continue;
        int widx = (oc*196 + iy*14 + 2*pox) >> 1;   // u32 index, even u16 base
        u32 wB = row32[widx];
        u32 c1 = wB & 0xffffu, c2 = wB >> 16;
        m = c1 > m ? c1 : m;
        m = c2 > m ? c2 : m;
        if (pox > 0){
          u32 wA = row32[widx - 1];
          u32 c0 = wA >> 16;
          m = c0 > m ? c0 : m;
        }
      }
      spool[((size_t)p*49 + pp)*128 + oc] = (u16)m;
      pox += 2; if (pox >= 7){ pox -= 7; ++poy; }
    }
  }
}

// ================= mega2: conv2 UNION big weight transposes (wvrT, wm1T, wsoT) ================
// conv2 iff (bid%7)==6 (cid=(bid-6)/7 < 500); else transpose tidx = bid - bid/7
__global__ __launch_bounds__(512) void k_mega2(
    const u16* __restrict__ spool, const u16* __restrict__ w2t, const float* __restrict__ b2,
    const float* __restrict__ g1, const float* __restrict__ be1,
    const float* __restrict__ stats1, const int* __restrict__ im_idx,
    float* __restrict__ segr, float* __restrict__ stats2, int P, float invN1,
    const float* __restrict__ w_vr, const float* __restrict__ w_m1,
    const float* __restrict__ w_subj, const float* __restrict__ w_obj,
    u16* __restrict__ wvrT, u16* __restrict__ wm1T, u16* __restrict__ wsoT){
  __shared__ f4v raw4[2852];                 // 45632 B
  int bid = blockIdx.x, t = threadIdx.x;

  if (bid % 7 != 6){
    float* tile = (float*)raw4;
    int tidx = bid - bid/7;
    if (tidx < 1568){
      transpose_body(w_vr, wvrT, 12544, 512, tidx >> 3, tidx & 7, t, 512, tile);
    } else if (tidx < 2336){
      int idx = tidx - 1568;
      transpose_body(w_m1, wm1T, 1536, 2048, idx >> 5, idx & 31, t, 512, tile);
    } else if (tidx < 2848){
      int idx = tidx - 2336;
      int sel = idx >> 8; idx &= 255;
      transpose_body(sel ? w_obj : w_subj, wsoT + (size_t)sel*512*2048,
                     2048, 512, idx >> 3, idx & 7, t, 512, tile);
    }
    return;
  }

  // ---------- conv2 (3x3 s1 p1, 128->256), 512 thr, 8 waves cover all 256 oc ----------
  u16* inT = (u16*)raw4;                       // [164 rows][136], row 162 zero
  float* sc1 = (float*)((char*)raw4 + 44608);
  float* sh1 = sc1 + 128;
  int cid = (bid - 6)/7;
  int b = cid/5, q = cid - (cid/5)*5;
  int lane = t & 63, w = t >> 6;
  int l15 = lane & 15, lhi = lane >> 4;
  {
    f4v z = {};
    for (int i = t; i < 2788; i += 512) raw4[i] = z;
  }
  if (t < 128){
    float mean = stats1[t]*invN1;
    float var  = stats1[128 + t]*invN1 - mean*mean;
    float sc = g1[t]*rsqrtf(var + 1e-5f);
    sc1[t] = sc; sh1[t] = be1[t] - mean*sc;
  }
  int s0, s1; segrange(im_idx, P, b, s0, s1);
  int cnt = s1 - s0, chunk = (cnt + 4)/5;
  int p0 = s0 + q*chunk, p1 = min(p0 + chunk, s1);
  int ocb = w*32;
  int pym[7], pxm[7], prm[7]; bool okm[7];
  #pragma unroll
  for (int mt = 0; mt < 7; ++mt){
    int row = mt*16 + l15;
    int pix = row >> 1; prm[mt] = row & 1;
    okm[mt] = pix < 49;
    pym[mt] = pix/7; pxm[mt] = pix - pym[mt]*7;
  }
  float bias[2];
  bias[0] = b2[ocb + l15]; bias[1] = b2[ocb + 16 + l15];
  f4v segacc[7][2] = {};
  float ssum[2] = {0,0}, ssq[2] = {0,0};
  for (int p = p0; p < p1; p += 2){
    __syncthreads();
    int hasB = (p + 1 < p1);
    for (int j = t; j < 6272; j += 512){
      int pp = j >= 3136;
      if (pp && !hasB) break;
      int i = j - pp*3136;
      u32 v = ((const u32*)(spool + (size_t)(p + pp)*6272))[i];
      int pix = i >> 6, icp = i & 63;
      float lo = b2f((u16)v)*sc1[icp*2]     + sh1[icp*2];
      float hi = b2f((u16)(v >> 16))*sc1[icp*2 + 1] + sh1[icp*2 + 1];
      int py = pix/7, pxx = pix - py*7;
      int row = ((py + 1)*9 + pxx + 1)*2 + pp;
      ((u32*)inT)[row*68 + icp] = (u32)f2b(lo) | ((u32)f2b(hi) << 16);
    }
    __syncthreads();
    f4v pacc[7][2] = {};
    #pragma unroll
    for (int tap = 0; tap < 9; ++tap){
      int dy = tap/3 - 1, dx = tap%3 - 1;
      int rowb[7];
      #pragma unroll
      for (int mt = 0; mt < 7; ++mt)
        rowb[mt] = okm[mt] ? (((pym[mt] + 1 + dy)*9 + pxm[mt] + 1 + dx)*2 + prm[mt])*136 : 162*136;
      s8v Bt[4][2];
      #pragma unroll
      for (int kst = 0; kst < 4; ++kst){
        int koff = kst*32 + lhi*8;
        Bt[kst][0] = *(const s8v*)&w2t[(size_t)(tap*256 + ocb + l15)*128 + koff];
        Bt[kst][1] = *(const s8v*)&w2t[(size_t)(tap*256 + ocb + 16 + l15)*128 + koff];
      }
      #pragma unroll
      for (int kst = 0; kst < 4; ++kst){
        int koff = kst*32 + lhi*8;
        #pragma unroll
        for (int mt = 0; mt < 7; ++mt){
          s8v A = *(const s8v*)&inT[rowb[mt] + koff];
          pacc[mt][0] = mfma16(A, Bt[kst][0], pacc[mt][0]);
          pacc[mt][1] = mfma16(A, Bt[kst][1], pacc[mt][1]);
        }
      }
    }
    #pragma unroll
    for (int n = 0; n < 2; ++n)
      #pragma unroll
      for (int mt = 0; mt < 7; ++mt)
        #pragma unroll
        for (int v = 0; v < 4; ++v){
          int row = mt*16 + lhi*4 + v;
          int pix = row >> 1, pr = row & 1;
          float r = fmaxf(pacc[mt][n][v] + bias[n], 0.f);
          r = (pix < 49 && (pr == 0 || hasB)) ? r : 0.f;
          segacc[mt][n][v] += r;
          ssum[n] += r; ssq[n] += r*r;
        }
  }
  #pragma unroll
  for (int n = 0; n < 2; ++n){
    int oc = ocb + n*16 + l15;
    #pragma unroll
    for (int mt = 0; mt < 7; ++mt){
      int pix0 = (mt*16 + lhi*4) >> 1;
      if (pix0 < 49)
        atomicAdd(&segr[(size_t)(b*256 + oc)*49 + pix0], segacc[mt][n][0] + segacc[mt][n][1]);
      if (pix0 + 1 < 49)
        atomicAdd(&segr[(size_t)(b*256 + oc)*49 + pix0 + 1], segacc[mt][n][2] + segacc[mt][n][3]);
    }
    float s = ssum[n], qd = ssq[n];
    s  += __shfl_xor(s, 16);  s  += __shfl_xor(s, 32);
    qd += __shfl_xor(qd, 16); qd += __shfl_xor(qd, 32);
    if (lane < 16){
      atomicAdd(&stats2[ocb + n*16 + lane], s);
      atomicAdd(&stats2[256 + ocb + n*16 + lane], qd);
    }
  }
}

// ================= combine: union 1x1 conv + bn2(seg-mean relu2) -> tbf =======================
__global__ __launch_bounds__(256) void k_combine(const u16* __restrict__ muT, const u16* __restrict__ wuT,
                                                 const float* __restrict__ b_u, const float* __restrict__ segr,
                                                 const float* __restrict__ stats2,
                                                 const float* __restrict__ g2, const float* __restrict__ be2,
                                                 const int* __restrict__ im_idx, u16* __restrict__ tbf,
                                                 int P, float invN2){
  __shared__ float sc2[256], sh2[256];
  int b = blockIdx.x, t = threadIdx.x;
  int lane = t & 63, w = t >> 6;
  int l15 = lane & 15, lhi = lane >> 4;
  {
    float mean = stats2[t]*invN2;
    float var  = stats2[256 + t]*invN2 - mean*mean;
    float sc = g2[t]*rsqrtf(var + 1e-5f);
    sc2[t] = sc; sh2[t] = be2[t] - mean*sc;
  }
  __syncthreads();
  int s0, s1; segrange(im_idx, P, b, s0, s1);
  float inv = 1.f / fmaxf((float)(s1 - s0), 1.f);
  int ocb = w*64;
  const u16* arow[4];
  #pragma unroll
  for (int mt = 0; mt < 4; ++mt){
    int pix = mt*16 + l15;
    arow[mt] = muT + (size_t)(b*49 + (pix < 49 ? pix : 0))*1024;
  }
  f4v acc[4][4] = {};
  for (int kst = 0; kst < 32; ++kst){
    int koff = kst*32 + lhi*8;
    s8v Bf[4];
    #pragma unroll
    for (int nt = 0; nt < 4; ++nt)
      Bf[nt] = *(const s8v*)&wuT[(ocb + nt*16 + l15)*1024 + koff];
    #pragma unroll
    for (int mt = 0; mt < 4; ++mt){
      s8v A = *(const s8v*)&arow[mt][koff];
      #pragma unroll
      for (int nt = 0; nt < 4; ++nt)
        acc[mt][nt] = mfma16(A, Bf[nt], acc[mt][nt]);
    }
  }
  #pragma unroll
  for (int nt = 0; nt < 4; ++nt){
    int oc = ocb + nt*16 + l15;
    float bu = b_u[oc], sc = sc2[oc], sh = sh2[oc];
    #pragma unroll
    for (int mt = 0; mt < 4; ++mt)
      #pragma unroll
      for (int v = 0; v < 4; ++v){
        int pix = mt*16 + lhi*4 + v;
        if (pix < 49){
          float val = acc[mt][nt][v] + bu + sc*segr[(size_t)(b*256 + oc)*49 + pix]*inv + sh;
          tbf[(size_t)b*12544 + oc*49 + pix] = f2b(val);
        }
      }
  }
}

// ================= mega3: vr GEMM (56 blocks) UNION subj/obj GEMM (16 blocks) ================
__global__ __launch_bounds__(256) void k_mega3(const u16* __restrict__ tbf, const u16* __restrict__ wvrT,
                                               const float* __restrict__ b_vr,
                                               const u16* __restrict__ pfbf, const u16* __restrict__ wsoT,
                                               const float* __restrict__ b_subj, const float* __restrict__ b_obj,
                                               float* __restrict__ px, int B){
  int bid = blockIdx.x, t = threadIdx.x;
  int lane = t & 63, w = t >> 6;
  int l15 = lane & 15, lhi = lane >> 4;
  if (bid < 56){
    int nb = bid & 1, kc = bid >> 1;
    int colb = nb*256 + w*64;
    int k0 = kc*448;
    f4v acc[7][4] = {};
    for (int kst = 0; kst < 14; ++kst){
      int koff = k0 + kst*32 + lhi*8;
      s8v Bf[4];
      #pragma unroll
      for (int nt = 0; nt < 4; ++nt)
        Bf[nt] = *(const s8v*)&wvrT[(size_t)(colb + nt*16 + l15)*12544 + koff];
      #pragma unroll
      for (int mt = 0; mt < 7; ++mt){
        s8v A = *(const s8v*)&tbf[(size_t)(mt*16 + l15)*12544 + koff];
        #pragma unroll
        for (int nt = 0; nt < 4; ++nt)
          acc[mt][nt] = mfma16(A, Bf[nt], acc[mt][nt]);
      }
    }
    #pragma unroll
    for (int nt = 0; nt < 4; ++nt){
      int col = colb + nt*16 + l15;
      float bias = (kc == 0) ? b_vr[col] : 0.f;
      #pragma unroll
      for (int mt = 0; mt < 7; ++mt)
        #pragma unroll
        for (int v = 0; v < 4; ++v){
          int row = mt*16 + lhi*4 + v;
          if (row < B) atomicAdd(&px[row*1536 + 1024 + col], acc[mt][nt][v] + bias);
        }
    }
  } else {
    int r = bid - 56;
    int nb = r & 1, s = (r >> 1) & 1, kc = r >> 2;
    int colb = nb*256 + w*64;
    int k0 = kc*512;
    const float* bi = s ? b_obj : b_subj;
    f4v acc[7][4] = {};
    for (int kst = 0; kst < 16; ++kst){
      int koff = k0 + kst*32 + lhi*8;
      s8v Bf[4];
      #pragma unroll
      for (int nt = 0; nt < 4; ++nt)
        Bf[nt] = *(const s8v*)&wsoT[(size_t)(s*512 + colb + nt*16 + l15)*2048 + koff];
      #pragma unroll
      for (int mt = 0; mt < 7; ++mt){
        int row = mt*16 + l15; row = row < B ? row : 0;
        s8v A = *(const s8v*)&pfbf[(size_t)(s*100 + row)*2048 + koff];
        #pragma unroll
        for (int nt = 0; nt < 4; ++nt)
          acc[mt][nt] = mfma16(A, Bf[nt], acc[mt][nt]);
      }
    }
    #pragma unroll
    for (int nt = 0; nt < 4; ++nt){
      int col = colb + nt*16 + l15;
      float bias = (kc == 0) ? bi[col] : 0.f;
      #pragma unroll
      for (int mt = 0; mt < 7; ++mt)
        #pragma unroll
        for (int v = 0; v < 4; ++v){
          int row = mt*16 + lhi*4 + v;
          if (row < B) atomicAdd(&px[row*1536 + s*512 + col], acc[mt][nt][v] + bias);
        }
    }
  }
}

// ================= MLP m1: [112,1536]@[1536,2048], k-split atomics, f32 A inline-cast =========
__global__ __launch_bounds__(256) void k_m1(const float* __restrict__ px, const u16* __restrict__ wm1T,
                                            float* __restrict__ h, int B){
  int nb = blockIdx.x, kc = blockIdx.y, t = threadIdx.x;
  int lane = t & 63, w = t >> 6;
  int l15 = lane & 15, lhi = lane >> 4;
  int colb = nb*256 + w*64;
  int k0 = kc*384;
  f4v acc[7][4] = {};
  for (int kst = 0; kst < 12; ++kst){
    int koff = k0 + kst*32 + lhi*8;
    s8v Bf[4];
    #pragma unroll
    for (int nt = 0; nt < 4; ++nt)
      Bf[nt] = *(const s8v*)&wm1T[(size_t)(colb + nt*16 + l15)*1536 + koff];
    #pragma unroll
    for (int mt = 0; mt < 7; ++mt){
      const float* ap = px + (size_t)(mt*16 + l15)*1536 + koff;
      f4v lo = *(const f4v*)ap;
      f4v hi = *(const f4v*)(ap + 4);
      s8v A;
      A[0] = (short)f2b(lo[0]); A[1] = (short)f2b(lo[1]);
      A[2] = (short)f2b(lo[2]); A[3] = (short)f2b(lo[3]);
      A[4] = (short)f2b(hi[0]); A[5] = (short)f2b(hi[1]);
      A[6] = (short)f2b(hi[2]); A[7] = (short)f2b(hi[3]);
      #pragma unroll
      for (int nt = 0; nt < 4; ++nt)
        acc[mt][nt] = mfma16(A, Bf[nt], acc[mt][nt]);
    }
  }
  #pragma unroll
  for (int nt = 0; nt < 4; ++nt){
    int col = colb + nt*16 + l15;
    #pragma unroll
    for (int mt = 0; mt < 7; ++mt)
      #pragma unroll
      for (int v = 0; v < 4; ++v){
        int row = mt*16 + lhi*4 + v;
        if (row < B) atomicAdd(&h[row*2048 + col], acc[mt][nt][v]);
      }
  }
}

// ================= m2 + bias1/relu + sigmoid, in-block k-split x2 ============================
__global__ __launch_bounds__(512) void k_m2(const float* __restrict__ h, const float* __restrict__ bm1,
                                            const float* __restrict__ w_m2, const float* __restrict__ b_m2,
                                            float* __restrict__ out){
  __shared__ float part[160];
  int b = blockIdx.x, t = threadIdx.x;
  int col = t & 255, kg = t >> 8;
  float acc = 0.f;
  if (col < 157){
    const float* hb = h + (size_t)b*2048;
    int k0 = kg*1024;
    for (int k = k0; k < k0 + 1024; ++k)
      acc += fmaxf(hb[k] + bm1[k], 0.f) * w_m2[(size_t)k*157 + col];
  }
  if (kg == 1 && col < 157) part[col] = acc;
  __syncthreads();
  if (kg == 0 && col < 157){
    float s = acc + part[col] + b_m2[col];
    out[b*157 + col] = 1.f/(1.f + expf(-s));
  }
}

extern "C" void kernel_launch(void* const* d_in, const int* in_sizes, int n_in,
                              void* d_out, int out_size, void* d_ws, size_t ws_size,
                              hipStream_t stream){
  const float* features   = (const float*)d_in[0];
  const float* union_feat = (const float*)d_in[1];
  const float* masks      = (const float*)d_in[2];
  const float* w_union    = (const float*)d_in[3];
  const float* b_union    = (const float*)d_in[4];
  const float* w_c1       = (const float*)d_in[5];
  const float* b_c1       = (const float*)d_in[6];
  const float* g_bn1      = (const float*)d_in[7];
  const float* be_bn1     = (const float*)d_in[8];
  const float* w_c2       = (const float*)d_in[9];
  const float* b_c2       = (const float*)d_in[10];
  const float* g_bn2      = (const float*)d_in[11];
  const float* be_bn2     = (const float*)d_in[12];
  const float* w_subj     = (const float*)d_in[13];
  const float* b_subj     = (const float*)d_in[14];
  const float* w_obj      = (const float*)d_in[15];
  const float* b_obj      = (const float*)d_in[16];
  const float* w_vr       = (const float*)d_in[17];
  const float* b_vr       = (const float*)d_in[18];
  const float* w_m1       = (const float*)d_in[19];
  const float* b_m1       = (const float*)d_in[20];
  const float* w_m2       = (const float*)d_in[21];
  const float* b_m2       = (const float*)d_in[22];
  const int* pair_idx     = (const int*)d_in[23];
  const int* im_idx       = (const int*)d_in[24];
  float* out = (float*)d_out;
  const int P = in_sizes[24];
  const int B = out_size/157;

  char* ws = (char*)d_ws;
  size_t off = 0;
  auto alloc = [&](size_t bytes)->size_t{ size_t o = off; off += (bytes + 255) & ~(size_t)255; return o; };
  // zero-region (one memset): stats | segr | px | h
  size_t o_stats= alloc(3072);
  size_t o_segr = alloc((size_t)B*256*49*4);
  size_t o_px   = alloc((size_t)112*1536*4);
  size_t o_h    = alloc((size_t)B*2048*4);
  size_t zero_end = off;
  size_t o_muT  = alloc((size_t)B*49*1024*2);
  size_t o_spool= alloc((size_t)P*49*128*2);
  size_t o_w1t  = alloc(128*128*2);
  size_t o_w2t  = alloc(9*256*128*2);
  size_t o_wuT  = alloc(256*1024*2);
  size_t o_wvrT = alloc((size_t)512*12544*2);
  size_t o_wm1T = alloc((size_t)2048*1536*2);
  size_t o_wsoT = alloc((size_t)1024*2048*2);
  size_t o_pfbf = alloc((size_t)200*2048*2);
  size_t o_tbf  = alloc((size_t)112*12544*2);
  (void)ws_size; (void)n_in;

  float* stats1 = (float*)(ws + o_stats);
  float* stats2 = stats1 + 256;
  u16*   muT    = (u16*)(ws + o_muT);
  u16*   spool  = (u16*)(ws + o_spool);
  u16*   w1t    = (u16*)(ws + o_w1t);
  u16*   w2t    = (u16*)(ws + o_w2t);
  u16*   wuT    = (u16*)(ws + o_wuT);
  u16*   wvrT   = (u16*)(ws + o_wvrT);
  u16*   wm1T   = (u16*)(ws + o_wm1T);
  u16*   wsoT   = (u16*)(ws + o_wsoT);
  u16*   pfbf   = (u16*)(ws + o_pfbf);
  float* segr   = (float*)(ws + o_segr);
  u16*   tbf    = (u16*)(ws + o_tbf);
  float* px     = (float*)(ws + o_px);
  float* h      = (float*)(ws + o_h);

  hipMemsetAsync(ws, 0, zero_end, stream);

  k_misc<<<2440, dim3(256), 0, stream>>>(features, pair_idx, im_idx, w_c1, w_c2, w_union,
                                         w1t, w2t, wuT, pfbf, P);
  k_mega1<<<6400, dim3(256), 0, stream>>>(masks, w1t, b_c1, stats1, spool,
                                          union_feat, im_idx, muT, P);
  k_mega2<<<3500, dim3(512), 0, stream>>>(spool, w2t, b_c2, g_bn1, be_bn1, stats1, im_idx,
                                          segr, stats2, P, 1.f/((float)P*196.f),
                                          w_vr, w_m1, w_subj, w_obj, wvrT, wm1T, wsoT);
  k_combine<<<B, dim3(256), 0, stream>>>(muT, wuT, b_union, segr, stats2, g_bn2, be_bn2, im_idx,
                                         tbf, P, 1.f/((float)P*49.f));
  k_mega3<<<72, dim3(256), 0, stream>>>(tbf, wvrT, b_vr, pfbf, wsoT, b_subj, b_obj, px, B);
  k_m1<<<dim3(8, 4), dim3(256), 0, stream>>>(px, wm1T, h, B);
  k_m2<<<B, dim3(512), 0, stream>>>(h, b_m1, w_m2, b_m2, out);
}

// Round 7
// 1253.769 us; speedup vs baseline: 1.4158x; 1.4158x over previous
//
#include <hip/hip_runtime.h>

typedef unsigned short u16;
typedef unsigned int   u32;
typedef short s8v __attribute__((ext_vector_type(8)));   // 8 x bf16 MFMA operand
typedef float f4v __attribute__((ext_vector_type(4)));   // MFMA accumulator

#define DEV __device__ __forceinline__

DEV u16 f2b(float f){
  u32 x = __builtin_bit_cast(u32, f);
  u32 r = x + 0x7fffu + ((x >> 16) & 1u);
  return (u16)(r >> 16);
}
DEV float b2f(u16 u){ u32 x = ((u32)u) << 16; return __builtin_bit_cast(float, x); }
DEV f4v mfma16(s8v a, s8v b, f4v c){ return __builtin_amdgcn_mfma_f32_16x16x32_bf16(a, b, c, 0, 0, 0); }

DEV void segrange(const int* __restrict__ im, int P, int b, int& s0, int& s1){
  int lo = 0, hi = P;
  while (lo < hi){ int m = (lo + hi) >> 1; if (im[m] < b) lo = m + 1; else hi = m; }
  s0 = lo;
  int lo2 = lo; hi = P;
  while (lo2 < hi){ int m = (lo2 + hi) >> 1; if (im[m] < b + 1) lo2 = m + 1; else hi = m; }
  s1 = lo2;
}

DEV void transpose_body(const float* __restrict__ src, u16* __restrict__ dst,
                        int R, int C, int rb, int cb, int t, float* tile){
  int r0 = rb << 6, c0 = cb << 6;
  for (int i = t; i < 4096; i += 256){
    int rl = i >> 6, cl = i & 63;
    tile[rl*65 + cl] = src[(size_t)(r0 + rl)*C + c0 + cl];
  }
  __syncthreads();
  for (int i = t; i < 4096; i += 256){
    int cl = i >> 6, rl = i & 63;
    dst[(size_t)(c0 + cl)*R + r0 + rl] = f2b(tile[rl*65 + cl]);
  }
}

// ============ k_misc: all weight transforms + feature segment-mean ============
// [0,64): w1tp  [64,1216): w2t  [1216,2240): wuT  [2240,3808): wvrT
// [3808,4576): wm1T  [4576,5088): wsoT  [5088,5288): featpool
__global__ __launch_bounds__(256) void k_misc(
    const float* __restrict__ feat, const int* __restrict__ pidx, const int* __restrict__ im_idx,
    const float* __restrict__ w_c1, const float* __restrict__ w_c2, const float* __restrict__ w_u,
    const float* __restrict__ w_vr, const float* __restrict__ w_m1,
    const float* __restrict__ w_subj, const float* __restrict__ w_obj,
    u16* __restrict__ w1tp, u16* __restrict__ w2t, u16* __restrict__ wuT,
    u16* __restrict__ wvrT, u16* __restrict__ wm1T, u16* __restrict__ wsoT,
    u16* __restrict__ pfbf, int P){
  __shared__ float smem[4160];
  int bid = blockIdx.x, t = threadIdx.x;
  if (bid < 64){
    int i = bid*256 + t;                   // i = oc*128 + k', k' = ic*64 + ky*8 + kx
    int kp = i & 127;
    int kx = kp & 7, ky = (kp >> 3) & 7, ic = kp >> 6;
    int oc = i >> 7;
    w1tp[i] = f2b((kx < 7 && ky < 7) ? w_c1[oc*98 + ic*49 + ky*7 + kx] : 0.f);
  } else if (bid < 1216){
    int i = (bid - 64)*256 + t;            // [9 tap][256 oc][128 ic]
    int tap = i >> 15, r = i & 32767;
    w2t[i] = f2b(w_c2[((r>>7)*128 + (r & 127))*9 + tap]);
  } else if (bid < 2240){
    int i = (bid - 1216)*256 + t;
    wuT[i] = f2b(w_u[i]);
  } else if (bid < 3808){
    int idx = bid - 2240;                  // 196*8
    transpose_body(w_vr, wvrT, 12544, 512, idx >> 3, idx & 7, t, smem);
  } else if (bid < 4576){
    int idx = bid - 3808;                  // 24*32
    transpose_body(w_m1, wm1T, 1536, 2048, idx >> 5, idx & 31, t, smem);
  } else if (bid < 5088){
    int idx = bid - 4576;                  // 2 * 32*8
    int sel = idx >> 8; idx &= 255;
    transpose_body(sel ? w_obj : w_subj, wsoT + (size_t)sel*512*2048,
                   2048, 512, idx >> 3, idx & 7, t, smem);
  } else {
    int i = bid - 5088; int s = i/100, b = i - s*100;
    int s0, s1; segrange(im_idx, P, b, s0, s1);
    float inv = 1.f / fmaxf((float)(s1 - s0), 1.f);
    f4v a0 = {}, a1 = {};
    for (int p = s0; p < s1; ++p){
      int row = pidx[p*2 + s];
      const f4v* src = (const f4v*)(feat + (size_t)row*2048);
      a0 += src[t]; a1 += src[t+256];
    }
    u16* dst = pfbf + (size_t)(s*100 + b)*2048;
    #pragma unroll
    for (int j = 0; j < 4; ++j){
      dst[4*t + j]        = f2b(a0[j]*inv);
      dst[1024 + 4*t + j] = f2b(a1[j]*inv);
    }
  }
}

// ============ k_upool: union segment-mean -> muT[b][49][1024] bf16 (HBM-bound) ============
__global__ __launch_bounds__(256) void k_upool(const float* __restrict__ uf, const int* __restrict__ im_idx,
                                               u16* __restrict__ muT, int P){
  __shared__ float smem[3136];
  int b = blockIdx.x, icb = blockIdx.y, t = threadIdx.x;
  int s0, s1; segrange(im_idx, P, b, s0, s1);
  float inv = 1.f / fmaxf((float)(s1 - s0), 1.f);
  f4v a0 = {}, a1 = {}, a2 = {}, a3 = {};
  int p = s0;
  for (; p + 1 < s1; p += 2){
    const f4v* x = (const f4v*)(uf + (size_t)p*50176 + icb*3136);
    const f4v* y = (const f4v*)(uf + (size_t)(p+1)*50176 + icb*3136);
    a0 += x[t] + y[t]; a1 += x[t+256] + y[t+256]; a2 += x[t+512] + y[t+512];
    if (t < 16) a3 += x[t+768] + y[t+768];
  }
  if (p < s1){
    const f4v* x = (const f4v*)(uf + (size_t)p*50176 + icb*3136);
    a0 += x[t]; a1 += x[t+256]; a2 += x[t+512];
    if (t < 16) a3 += x[t+768];
  }
  *(f4v*)&smem[4*t] = a0;
  *(f4v*)&smem[4*(t+256)] = a1;
  *(f4v*)&smem[4*(t+512)] = a2;
  if (t < 16) *(f4v*)&smem[4*(t+768)] = a3;
  __syncthreads();
  for (int o = t; o < 3136; o += 256){
    int pix = o >> 6, ics = o & 63;
    muT[(size_t)(b*49 + pix)*1024 + (icb<<6) + ics] = f2b(smem[ics*49 + pix]*inv);
  }
}

// ============ conv1 v2 (7x7 s2 p3, 2->128): weight-permuted direct-LDS-read MFMA ============
// grid (P, 2): z = oc-half. LDS 30.7KB -> 5 blocks/CU. No im2col buffer.
// k' = ic*64 + ky*8 + kx; input staged [2][34][40] u16 zero-padded (1360 u32); A-frag = 4x ds_read_b32.
__global__ __launch_bounds__(256) void k_conv1(const float* __restrict__ masks, const u16* __restrict__ w1tp,
                                               const float* __restrict__ b1,
                                               float* __restrict__ stats1, u16* __restrict__ spool){
  __shared__ u32 lds32[1400];              // in_bf: 2 ch x 680 u32 (+40 slack for ky=7/pad reads)
  __shared__ u16 s1n[64*196];              // this block's 64 oc, post-relu PRE-BN
  int p = blockIdx.x, z = blockIdx.y, t = threadIdx.x;
  int lane = t & 63, w = t >> 6;
  int l15 = lane & 15, lhi = lane >> 4;
  int ocl = w*16 + l15;                    // oc within this half [0,64)
  int oc  = z*64 + ocl;                    // global oc
  s8v Bf[4];
  #pragma unroll
  for (int kst = 0; kst < 4; ++kst)
    Bf[kst] = *(const s8v*)&w1tp[(size_t)oc*128 + kst*32 + lhi*8];
  for (int i = t; i < 1400; i += 256) lds32[i] = 0;
  __syncthreads();
  u16* in_bf = (u16*)lds32;
  for (int e = t; e < 1458; e += 256){
    int c = e >= 729; int r = e - c*729;
    int rr = r/27, cc = r - rr*27;
    in_bf[c*1360 + (rr + 3)*40 + cc + 3] = f2b(masks[(size_t)p*1458 + e]);
  }
  int rb[13];
  #pragma unroll
  for (int mt = 0; mt < 13; ++mt){
    int pix = mt*16 + l15;
    int oy = pix/14, ox = pix - oy*14;
    rb[mt] = oy*40 + ox;                   // u32 index: oy*2 rows x 20 u32 + ox (col ox*2 u16)
  }
  __syncthreads();
  f4v acc[13] = {};
  #pragma unroll
  for (int kst = 0; kst < 4; ++kst){
    int kk = kst*32 + lhi*8;
    int kbase = (kk >> 6)*680 + ((kk >> 3) & 7)*20;   // ic*680 + ky*20 (u32)
    #pragma unroll
    for (int mt = 0; mt < 13; ++mt){
      int a = kbase + rb[mt];
      union { u32 u[4]; s8v v; } cv;
      cv.u[0] = lds32[a];   cv.u[1] = lds32[a+1];
      cv.u[2] = lds32[a+2]; cv.u[3] = lds32[a+3];
      acc[mt] = mfma16(cv.v, Bf[kst], acc[mt]);
    }
  }
  // epilogue: bias+relu -> stats + s1n (s1n disjoint from in_bf)
  float bias = b1[oc];
  float ss = 0.f, qq = 0.f;
  #pragma unroll
  for (int mt = 0; mt < 13; ++mt)
    #pragma unroll
    for (int v = 0; v < 4; ++v){
      int pix = mt*16 + lhi*4 + v;
      if (pix < 196){
        float r = fmaxf(acc[mt][v] + bias, 0.f);
        ss += r; qq += r*r;
        s1n[ocl*196 + pix] = f2b(r);
      }
    }
  ss += __shfl_xor(ss, 16); ss += __shfl_xor(ss, 32);
  qq += __shfl_xor(qq, 16); qq += __shfl_xor(qq, 32);
  if (lane < 16){
    atomicAdd(&stats1[z*64 + w*16 + lane], ss);
    atomicAdd(&stats1[128 + z*64 + w*16 + lane], qq);
  }
  __syncthreads();
  {  // maxpool 3x3 s2 p1 on 14x14 -> 7x7, u16-bit-compare (relu => monotone), u32-pair reads
    int ocp = t & 63, pg = t >> 6;
    const u32* row32 = (const u32*)s1n;
    for (int pp = pg; pp < 49; pp += 4){
      int poy = pp/7, pox = pp - poy*7;
      u32 m = 0;
      #pragma unroll
      for (int dy = 0; dy < 3; ++dy){
        int iy = poy*2 - 1 + dy;
        if (iy < 0 || iy > 13) continue;
        int widx = ocp*98 + iy*7 + pox;
        u32 wB = row32[widx];
        u32 c1 = wB & 0xffffu, c2 = wB >> 16;
        m = c1 > m ? c1 : m;
        m = c2 > m ? c2 : m;
        if (pox > 0){
          u32 c0 = row32[widx - 1] >> 16;
          m = c0 > m ? c0 : m;
        }
      }
      spool[((size_t)p*49 + pp)*128 + z*64 + ocp] = (u16)m;
    }
  }
}

// ============ conv2 (3x3 s1 p1, 128->256): BN1 on staging, per-tap B-batch (R4 struct) ============
__global__ __launch_bounds__(256) void k_conv2(const u16* __restrict__ spool, const u16* __restrict__ w2t,
                                               const float* __restrict__ b2,
                                               const float* __restrict__ g1, const float* __restrict__ be1,
                                               const float* __restrict__ stats1, const int* __restrict__ im_idx,
                                               float* __restrict__ segr, float* __restrict__ stats2,
                                               int P, float invN1){
  __shared__ u16 inT[164*136];
  __shared__ float sc1[128], sh1[128];
  int b = blockIdx.x, q = blockIdx.y, t = threadIdx.x;
  int lane = t & 63, w = t >> 6;
  int l15 = lane & 15, lhi = lane >> 4;
  {
    f4v z = {}; f4v* a4 = (f4v*)inT;
    for (int i = t; i < 2788; i += 256) a4[i] = z;
  }
  if (t < 128){
    float mean = stats1[t]*invN1;
    float var  = stats1[128 + t]*invN1 - mean*mean;
    float sc = g1[t]*rsqrtf(var + 1e-5f);
    sc1[t] = sc; sh1[t] = be1[t] - mean*sc;
  }
  int s0, s1; segrange(im_idx, P, b, s0, s1);
  int cnt = s1 - s0, chunk = (cnt + 4)/5;
  int p0 = s0 + q*chunk, p1 = min(p0 + chunk, s1);
  int ocb = blockIdx.z*128 + w*32;
  int pym[7], pxm[7], prm[7]; bool okm[7];
  #pragma unroll
  for (int mt = 0; mt < 7; ++mt){
    int row = mt*16 + l15;
    int pix = row >> 1; prm[mt] = row & 1;
    okm[mt] = pix < 49;
    pym[mt] = pix/7; pxm[mt] = pix - pym[mt]*7;
  }
  float bias[2];
  bias[0] = b2[ocb + l15]; bias[1] = b2[ocb + 16 + l15];
  f4v segacc[7][2] = {};
  float ssum[2] = {0,0}, ssq[2] = {0,0};
  for (int p = p0; p < p1; p += 2){
    __syncthreads();
    int hasB = (p + 1 < p1);
    for (int j = t; j < 6272; j += 256){
      int pp = j >= 3136;
      if (pp && !hasB) break;
      int i = j - pp*3136;
      u32 v = ((const u32*)(spool + (size_t)(p + pp)*6272))[i];
      int pix = i >> 6, icp = i & 63;
      float lo = b2f((u16)v)*sc1[icp*2]     + sh1[icp*2];
      float hi = b2f((u16)(v >> 16))*sc1[icp*2 + 1] + sh1[icp*2 + 1];
      int py = pix/7, pxx = pix - py*7;
      int row = ((py + 1)*9 + pxx + 1)*2 + pp;
      ((u32*)inT)[row*68 + icp] = (u32)f2b(lo) | ((u32)f2b(hi) << 16);
    }
    __syncthreads();
    f4v pacc[7][2] = {};
    #pragma unroll
    for (int tap = 0; tap < 9; ++tap){
      int dy = tap/3 - 1, dx = tap%3 - 1;
      int rowb[7];
      #pragma unroll
      for (int mt = 0; mt < 7; ++mt)
        rowb[mt] = okm[mt] ? (((pym[mt] + 1 + dy)*9 + pxm[mt] + 1 + dx)*2 + prm[mt])*136 : 162*136;
      s8v Bt[4][2];
      #pragma unroll
      for (int kst = 0; kst < 4; ++kst){
        int koff = kst*32 + lhi*8;
        Bt[kst][0] = *(const s8v*)&w2t[(size_t)(tap*256 + ocb + l15)*128 + koff];
        Bt[kst][1] = *(const s8v*)&w2t[(size_t)(tap*256 + ocb + 16 + l15)*128 + koff];
      }
      #pragma unroll
      for (int kst = 0; kst < 4; ++kst){
        int koff = kst*32 + lhi*8;
        #pragma unroll
        for (int mt = 0; mt < 7; ++mt){
          s8v A = *(const s8v*)&inT[rowb[mt] + koff];
          pacc[mt][0] = mfma16(A, Bt[kst][0], pacc[mt][0]);
          pacc[mt][1] = mfma16(A, Bt[kst][1], pacc[mt][1]);
        }
      }
    }
    #pragma unroll
    for (int n = 0; n < 2; ++n)
      #pragma unroll
      for (int mt = 0; mt < 7; ++mt)
        #pragma unroll
        for (int v = 0; v < 4; ++v){
          int row = mt*16 + lhi*4 + v;
          int pix = row >> 1, pr = row & 1;
          float r = fmaxf(pacc[mt][n][v] + bias[n], 0.f);
          r = (pix < 49 && (pr == 0 || hasB)) ? r : 0.f;
          segacc[mt][n][v] += r;
          ssum[n] += r; ssq[n] += r*r;
        }
  }
  #pragma unroll
  for (int n = 0; n < 2; ++n){
    int oc = ocb + n*16 + l15;
    #pragma unroll
    for (int mt = 0; mt < 7; ++mt){
      int pix0 = (mt*16 + lhi*4) >> 1;
      if (pix0 < 49)
        atomicAdd(&segr[(size_t)(b*256 + oc)*49 + pix0], segacc[mt][n][0] + segacc[mt][n][1]);
      if (pix0 + 1 < 49)
        atomicAdd(&segr[(size_t)(b*256 + oc)*49 + pix0 + 1], segacc[mt][n][2] + segacc[mt][n][3]);
    }
    float s = ssum[n], qd = ssq[n];
    s  += __shfl_xor(s, 16);  s  += __shfl_xor(s, 32);
    qd += __shfl_xor(qd, 16); qd += __shfl_xor(qd, 32);
    if (lane < 16){
      atomicAdd(&stats2[ocb + n*16 + lane], s);
      atomicAdd(&stats2[256 + ocb + n*16 + lane], qd);
    }
  }
}

// ============ combine: union 1x1 conv + bn2(seg-mean relu2) -> tbf ============
__global__ __launch_bounds__(256) void k_combine(const u16* __restrict__ muT, const u16* __restrict__ wuT,
                                                 const float* __restrict__ b_u, const float* __restrict__ segr,
                                                 const float* __restrict__ stats2,
                                                 const float* __restrict__ g2, const float* __restrict__ be2,
                                                 const int* __restrict__ im_idx, u16* __restrict__ tbf,
                                                 int P, float invN2){
  __shared__ float sc2[256], sh2[256];
  int b = blockIdx.x, t = threadIdx.x;
  int lane = t & 63, w = t >> 6;
  int l15 = lane & 15, lhi = lane >> 4;
  {
    float mean = stats2[t]*invN2;
    float var  = stats2[256 + t]*invN2 - mean*mean;
    float sc = g2[t]*rsqrtf(var + 1e-5f);
    sc2[t] = sc; sh2[t] = be2[t] - mean*sc;
  }
  __syncthreads();
  int s0, s1; segrange(im_idx, P, b, s0, s1);
  float inv = 1.f / fmaxf((float)(s1 - s0), 1.f);
  int ocb = w*64;
  const u16* arow[4];
  #pragma unroll
  for (int mt = 0; mt < 4; ++mt){
    int pix = mt*16 + l15;
    arow[mt] = muT + (size_t)(b*49 + (pix < 49 ? pix : 0))*1024;
  }
  f4v acc[4][4] = {};
  for (int kst = 0; kst < 32; ++kst){
    int koff = kst*32 + lhi*8;
    s8v Bf[4];
    #pragma unroll
    for (int nt = 0; nt < 4; ++nt)
      Bf[nt] = *(const s8v*)&wuT[(ocb + nt*16 + l15)*1024 + koff];
    #pragma unroll
    for (int mt = 0; mt < 4; ++mt){
      s8v A = *(const s8v*)&arow[mt][koff];
      #pragma unroll
      for (int nt = 0; nt < 4; ++nt)
        acc[mt][nt] = mfma16(A, Bf[nt], acc[mt][nt]);
    }
  }
  #pragma unroll
  for (int nt = 0; nt < 4; ++nt){
    int oc = ocb + nt*16 + l15;
    float bu = b_u[oc], sc = sc2[oc], sh = sh2[oc];
    #pragma unroll
    for (int mt = 0; mt < 4; ++mt)
      #pragma unroll
      for (int v = 0; v < 4; ++v){
        int pix = mt*16 + lhi*4 + v;
        if (pix < 49){
          float val = acc[mt][nt][v] + bu + sc*segr[(size_t)(b*256 + oc)*49 + pix]*inv + sh;
          tbf[(size_t)b*12544 + oc*49 + pix] = f2b(val);
        }
      }
  }
}

// ============ mega3: vr GEMM (56 blocks) UNION subj/obj GEMM (16 blocks) ============
__global__ __launch_bounds__(256) void k_mega3(const u16* __restrict__ tbf, const u16* __restrict__ wvrT,
                                               const float* __restrict__ b_vr,
                                               const u16* __restrict__ pfbf, const u16* __restrict__ wsoT,
                                               const float* __restrict__ b_subj, const float* __restrict__ b_obj,
                                               float* __restrict__ px, int B){
  int bid = blockIdx.x, t = threadIdx.x;
  int lane = t & 63, w = t >> 6;
  int l15 = lane & 15, lhi = lane >> 4;
  if (bid < 56){
    int nb = bid & 1, kc = bid >> 1;
    int colb = nb*256 + w*64;
    int k0 = kc*448;
    f4v acc[7][4] = {};
    for (int kst = 0; kst < 14; ++kst){
      int koff = k0 + kst*32 + lhi*8;
      s8v Bf[4];
      #pragma unroll
      for (int nt = 0; nt < 4; ++nt)
        Bf[nt] = *(const s8v*)&wvrT[(size_t)(colb + nt*16 + l15)*12544 + koff];
      #pragma unroll
      for (int mt = 0; mt < 7; ++mt){
        s8v A = *(const s8v*)&tbf[(size_t)(mt*16 + l15)*12544 + koff];
        #pragma unroll
        for (int nt = 0; nt < 4; ++nt)
          acc[mt][nt] = mfma16(A, Bf[nt], acc[mt][nt]);
      }
    }
    #pragma unroll
    for (int nt = 0; nt < 4; ++nt){
      int col = colb + nt*16 + l15;
      float bias = (kc == 0) ? b_vr[col] : 0.f;
      #pragma unroll
      for (int mt = 0; mt < 7; ++mt)
        #pragma unroll
        for (int v = 0; v < 4; ++v){
          int row = mt*16 + lhi*4 + v;
          if (row < B) atomicAdd(&px[row*1536 + 1024 + col], acc[mt][nt][v] + bias);
        }
    }
  } else {
    int r = bid - 56;
    int nb = r & 1, s = (r >> 1) & 1, kc = r >> 2;
    int colb = nb*256 + w*64;
    int k0 = kc*512;
    const float* bi = s ? b_obj : b_subj;
    f4v acc[7][4] = {};
    for (int kst = 0; kst < 16; ++kst){
      int koff = k0 + kst*32 + lhi*8;
      s8v Bf[4];
      #pragma unroll
      for (int nt = 0; nt < 4; ++nt)
        Bf[nt] = *(const s8v*)&wsoT[(size_t)(s*512 + colb + nt*16 + l15)*2048 + koff];
      #pragma unroll
      for (int mt = 0; mt < 7; ++mt){
        int row = mt*16 + l15; row = row < B ? row : 0;
        s8v A = *(const s8v*)&pfbf[(size_t)(s*100 + row)*2048 + koff];
        #pragma unroll
        for (int nt = 0; nt < 4; ++nt)
          acc[mt][nt] = mfma16(A, Bf[nt], acc[mt][nt]);
      }
    }
    #pragma unroll
    for (int nt = 0; nt < 4; ++nt){
      int col = colb + nt*16 + l15;
      float bias = (kc == 0) ? bi[col] : 0.f;
      #pragma unroll
      for (int mt = 0; mt < 7; ++mt)
        #pragma unroll
        for (int v = 0; v < 4; ++v){
          int row = mt*16 + lhi*4 + v;
          if (row < B) atomicAdd(&px[row*1536 + s*512 + col], acc[mt][nt][v] + bias);
        }
    }
  }
}

// ============ MLP m1: [112,1536]@[1536,2048], k-split atomics, f32 A inline-cast ============
__global__ __launch_bounds__(256) void k_m1(const float* __restrict__ px, const u16* __restrict__ wm1T,
                                            float* __restrict__ h, int B){
  int nb = blockIdx.x, kc = blockIdx.y, t = threadIdx.x;
  int lane = t & 63, w = t >> 6;
  int l15 = lane & 15, lhi = lane >> 4;
  int colb = nb*256 + w*64;
  int k0 = kc*384;
  f4v acc[7][4] = {};
  for (int kst = 0; kst < 12; ++kst){
    int koff = k0 + kst*32 + lhi*8;
    s8v Bf[4];
    #pragma unroll
    for (int nt = 0; nt < 4; ++nt)
      Bf[nt] = *(const s8v*)&wm1T[(size_t)(colb + nt*16 + l15)*1536 + koff];
    #pragma unroll
    for (int mt = 0; mt < 7; ++mt){
      const float* ap = px + (size_t)(mt*16 + l15)*1536 + koff;
      f4v lo = *(const f4v*)ap;
      f4v hi = *(const f4v*)(ap + 4);
      s8v A;
      A[0] = (short)f2b(lo[0]); A[1] = (short)f2b(lo[1]);
      A[2] = (short)f2b(lo[2]); A[3] = (short)f2b(lo[3]);
      A[4] = (short)f2b(hi[0]); A[5] = (short)f2b(hi[1]);
      A[6] = (short)f2b(hi[2]); A[7] = (short)f2b(hi[3]);
      #pragma unroll
      for (int nt = 0; nt < 4; ++nt)
        acc[mt][nt] = mfma16(A, Bf[nt], acc[mt][nt]);
    }
  }
  #pragma unroll
  for (int nt = 0; nt < 4; ++nt){
    int col = colb + nt*16 + l15;
    #pragma unroll
    for (int mt = 0; mt < 7; ++mt)
      #pragma unroll
      for (int v = 0; v < 4; ++v){
        int row = mt*16 + lhi*4 + v;
        if (row < B) atomicAdd(&h[row*2048 + col], acc[mt][nt][v]);
      }
  }
}

// ============ m2 + bias1/relu + sigmoid, in-block k-split x2 ============
__global__ __launch_bounds__(512) void k_m2(const float* __restrict__ h, const float* __restrict__ bm1,
                                            const float* __restrict__ w_m2, const float* __restrict__ b_m2,
                                            float* __restrict__ out){
  __shared__ float part[160];
  int b = blockIdx.x, t = threadIdx.x;
  int col = t & 255, kg = t >> 8;
  float acc = 0.f;
  if (col < 157){
    const float* hb = h + (size_t)b*2048;
    int k0 = kg*1024;
    for (int k = k0; k < k0 + 1024; ++k)
      acc += fmaxf(hb[k] + bm1[k], 0.f) * w_m2[(size_t)k*157 + col];
  }
  if (kg == 1 && col < 157) part[col] = acc;
  __syncthreads();
  if (kg == 0 && col < 157){
    float s = acc + part[col] + b_m2[col];
    out[b*157 + col] = 1.f/(1.f + expf(-s));
  }
}

extern "C" void kernel_launch(void* const* d_in, const int* in_sizes, int n_in,
                              void* d_out, int out_size, void* d_ws, size_t ws_size,
                              hipStream_t stream){
  const float* features   = (const float*)d_in[0];
  const float* union_feat = (const float*)d_in[1];
  const float* masks      = (const float*)d_in[2];
  const float* w_union    = (const float*)d_in[3];
  const float* b_union    = (const float*)d_in[4];
  const float* w_c1       = (const float*)d_in[5];
  const float* b_c1       = (const float*)d_in[6];
  const float* g_bn1      = (const float*)d_in[7];
  const float* be_bn1     = (const float*)d_in[8];
  const float* w_c2       = (const float*)d_in[9];
  const float* b_c2       = (const float*)d_in[10];
  const float* g_bn2      = (const float*)d_in[11];
  const float* be_bn2     = (const float*)d_in[12];
  const float* w_subj     = (const float*)d_in[13];
  const float* b_subj     = (const float*)d_in[14];
  const float* w_obj      = (const float*)d_in[15];
  const float* b_obj      = (const float*)d_in[16];
  const float* w_vr       = (const float*)d_in[17];
  const float* b_vr       = (const float*)d_in[18];
  const float* w_m1       = (const float*)d_in[19];
  const float* b_m1       = (const float*)d_in[20];
  const float* w_m2       = (const float*)d_in[21];
  const float* b_m2       = (const float*)d_in[22];
  const int* pair_idx     = (const int*)d_in[23];
  const int* im_idx       = (const int*)d_in[24];
  float* out = (float*)d_out;
  const int P = in_sizes[24];
  const int B = out_size/157;

  char* ws = (char*)d_ws;
  size_t off = 0;
  auto alloc = [&](size_t bytes)->size_t{ size_t o = off; off += (bytes + 255) & ~(size_t)255; return o; };
  // zero-region (one memset): stats | segr | px | h
  size_t o_stats= alloc(3072);
  size_t o_segr = alloc((size_t)B*256*49*4);
  size_t o_px   = alloc((size_t)112*1536*4);
  size_t o_h    = alloc((size_t)B*2048*4);
  size_t zero_end = off;
  size_t o_muT  = alloc((size_t)B*49*1024*2);
  size_t o_spool= alloc((size_t)P*49*128*2);
  size_t o_w1t  = alloc(128*128*2);
  size_t o_w2t  = alloc(9*256*128*2);
  size_t o_wuT  = alloc(256*1024*2);
  size_t o_wvrT = alloc((size_t)512*12544*2);
  size_t o_wm1T = alloc((size_t)2048*1536*2);
  size_t o_wsoT = alloc((size_t)1024*2048*2);
  size_t o_pfbf = alloc((size_t)200*2048*2);
  size_t o_tbf  = alloc((size_t)112*12544*2);
  (void)ws_size; (void)n_in;

  float* stats1 = (float*)(ws + o_stats);
  float* stats2 = stats1 + 256;
  u16*   muT    = (u16*)(ws + o_muT);
  u16*   spool  = (u16*)(ws + o_spool);
  u16*   w1tp   = (u16*)(ws + o_w1t);
  u16*   w2t    = (u16*)(ws + o_w2t);
  u16*   wuT    = (u16*)(ws + o_wuT);
  u16*   wvrT   = (u16*)(ws + o_wvrT);
  u16*   wm1T   = (u16*)(ws + o_wm1T);
  u16*   wsoT   = (u16*)(ws + o_wsoT);
  u16*   pfbf   = (u16*)(ws + o_pfbf);
  float* segr   = (float*)(ws + o_segr);
  u16*   tbf    = (u16*)(ws + o_tbf);
  float* px     = (float*)(ws + o_px);
  float* h      = (float*)(ws + o_h);

  hipMemsetAsync(ws, 0, zero_end, stream);

  k_misc<<<5288, dim3(256), 0, stream>>>(features, pair_idx, im_idx, w_c1, w_c2, w_union,
                                         w_vr, w_m1, w_subj, w_obj,
                                         w1tp, w2t, wuT, wvrT, wm1T, wsoT, pfbf, P);
  k_upool<<<dim3(B, 16), dim3(256), 0, stream>>>(union_feat, im_idx, muT, P);
  k_conv1<<<dim3(P, 2), dim3(256), 0, stream>>>(masks, w1tp, b_c1, stats1, spool);
  k_conv2<<<dim3(B, 5, 2), dim3(256), 0, stream>>>(spool, w2t, b_c2, g_bn1, be_bn1, stats1, im_idx,
                                                   segr, stats2, P, 1.f/((float)P*196.f));
  k_combine<<<B, dim3(256), 0, stream>>>(muT, wuT, b_union, segr, stats2, g_bn2, be_bn2, im_idx,
                                         tbf, P, 1.f/((float)P*49.f));
  k_mega3<<<72, dim3(256), 0, stream>>>(tbf, wvrT, b_vr, pfbf, wsoT, b_subj, b_obj, px, B);
  k_m1<<<dim3(8, 4), dim3(256), 0, stream>>>(px, wm1T, h, B);
  k_m2<<<B, dim3(512), 0, stream>>>(h, b_m1, w_m2, b_m2, out);
}